// Round 12
// baseline (285.786 us; speedup 1.0000x reference)
//
#include <hip/hip_runtime.h>
#include <math.h>

// Problem constants (from reference)
#define N_NODES 50000
#define N_EDGES 800000
#define ET (N_EDGES + N_NODES)   // edges + self loops = 850000
#define IN_DIM 128
#define HID 128
#define OUT_DIM 64
#define BW 64                              // bucket width (dst nodes)
#define NBUCK ((N_NODES + BW - 1) / BW)    // 782 buckets
#define NBLK 256                           // partition blocks
#define EPB 3328                           // edges per partition block (13*256)

__device__ __forceinline__ float lrelu(float x){ return x >= 0.f ? x : 0.2f * x; }
__device__ __forceinline__ float eluf(float x){ return x > 0.f ? x : expm1f(x); }
// RNE float->bf16 (finite inputs)
__device__ __forceinline__ unsigned f2bf(float f){
    unsigned u = __float_as_uint(f);
    return (u + 0x7fffu + ((u >> 16) & 1u)) >> 16;
}
__device__ __forceinline__ float bflo(unsigned u){ return __uint_as_float(u << 16); }
__device__ __forceinline__ float bfhi(unsigned u){ return __uint_as_float(u & 0xffff0000u); }

// ---------------------------------------------------------------------------
// CSR build, atomic-free radix style (unchanged).
// ---------------------------------------------------------------------------
__global__ __launch_bounds__(256) void k_count(const int* __restrict__ dst, int* __restrict__ C)
{
    __shared__ int cnt[NBUCK];
    const int tid = threadIdx.x, blk = blockIdx.x;
    for (int i = tid; i < NBUCK; i += 256) cnt[i] = 0;
    __syncthreads();
    #pragma unroll
    for (int j = 0; j < EPB / 256; j++) {
        const int e = blk * EPB + j * 256 + tid;
        if (e < ET) {
            const int d = (e < N_EDGES) ? dst[e] : (e - N_EDGES);
            atomicAdd(&cnt[d >> 6], 1);
        }
    }
    __syncthreads();
    for (int b = tid; b < NBUCK; b += 256) C[b * NBLK + blk] = cnt[b];
}

__global__ __launch_bounds__(256) void k_bsumA(const int* __restrict__ C, int* __restrict__ bsum2)
{
    __shared__ int red[4];
    int v = C[blockIdx.x * NBLK + threadIdx.x];
    #pragma unroll
    for (int off = 32; off > 0; off >>= 1) v += __shfl_down(v, off);
    if ((threadIdx.x & 63) == 0) red[threadIdx.x >> 6] = v;
    __syncthreads();
    if (threadIdx.x == 0) bsum2[blockIdx.x] = red[0] + red[1] + red[2] + red[3];
}

__global__ __launch_bounds__(1024) void k_bscanB(const int* __restrict__ bsum2, int* __restrict__ boff2)
{
    __shared__ int part[1024];
    const int t = threadIdx.x;
    int v = (t < NBUCK) ? bsum2[t] : 0;
    part[t] = v;
    __syncthreads();
    #pragma unroll
    for (int d = 1; d < 1024; d <<= 1) {
        int add = (t >= d) ? part[t - d] : 0;
        __syncthreads();
        part[t] += add;
        __syncthreads();
    }
    if (t < NBUCK) boff2[t] = part[t] - v;   // exclusive
    if (t == 0) boff2[NBUCK] = ET;
}

__global__ __launch_bounds__(256) void k_cscanC(const int* __restrict__ C,
                                                const int* __restrict__ boff2,
                                                int* __restrict__ Cs)
{
    __shared__ int part[256];
    const int t = threadIdx.x, b = blockIdx.x;
    int v = C[b * NBLK + t];
    part[t] = v;
    __syncthreads();
    #pragma unroll
    for (int d = 1; d < 256; d <<= 1) {
        int add = (t >= d) ? part[t - d] : 0;
        __syncthreads();
        part[t] += add;
        __syncthreads();
    }
    Cs[b * NBLK + t] = boff2[b] + part[t] - v;
}

__global__ __launch_bounds__(256) void k_part2(const int* __restrict__ src,
                                               const int* __restrict__ dst,
                                               const int* __restrict__ Cs,
                                               uint2* __restrict__ part)
{
    __shared__ int base[NBUCK];
    __shared__ int cnt[NBUCK];
    const int tid = threadIdx.x, blk = blockIdx.x;
    for (int b = tid; b < NBUCK; b += 256) { base[b] = Cs[b * NBLK + blk]; cnt[b] = 0; }
    __syncthreads();
    #pragma unroll
    for (int j = 0; j < EPB / 256; j++) {
        const int e = blk * EPB + j * 256 + tid;
        if (e < ET) {
            int s, d;
            if (e < N_EDGES) { s = src[e]; d = dst[e]; } else { s = d = e - N_EDGES; }
            const int b = d >> 6;
            const int r = atomicAdd(&cnt[b], 1);
            part[base[b] + r] = make_uint2((unsigned)d, (unsigned)s);
        }
    }
}

__global__ __launch_bounds__(256) void k_scat2(const int* __restrict__ boff2,
                                               const uint2* __restrict__ part,
                                               int* __restrict__ rowptr,
                                               int* __restrict__ csr_src)
{
    __shared__ int cnt64[BW];
    __shared__ int nbase[BW];
    const int b = blockIdx.x, tid = threadIdx.x;
    const int n0 = b * BW;
    const int lo = boff2[b], hi = boff2[b + 1];
    if (tid < BW) cnt64[tid] = 0;
    __syncthreads();
    for (int i = lo + tid; i < hi; i += 256) {
        atomicAdd(&cnt64[part[i].x & (BW - 1)], 1);
    }
    __syncthreads();
    if (tid < BW) {
        int v = cnt64[tid];
        int incl = v;
        #pragma unroll
        for (int off = 1; off < 64; off <<= 1) {
            int t2 = __shfl_up(incl, off);
            if (tid >= off) incl += t2;
        }
        const int excl = incl - v;
        nbase[tid] = excl;
        const int n = n0 + tid;
        if (n < N_NODES) rowptr[n] = lo + excl;
        cnt64[tid] = 0;
    }
    if (b == 0 && tid == 0) rowptr[N_NODES] = ET;
    __syncthreads();
    for (int i = lo + tid; i < hi; i += 256) {
        const uint2 p = part[i];
        const int dn = (int)p.x & (BW - 1);
        const int r = atomicAdd(&cnt64[dn], 1);
        csr_src[lo + nbase[dn] + r] = (int)p.y;
    }
}

// ---------------------------------------------------------------------------
// K1: h1 = x @ W1 [N,128] -> bf16 table + fp32 logits.
// 64 nodes/block, 128 threads, 782 blocks; thread = 8 nodes x 8 ch;
// 4 k-chunks of 32, REGISTER DOUBLE-BUFFERED staging: chunk c+1's global
// loads issue before chunk c's compute -> latency hidden behind FMAs.
// ---------------------------------------------------------------------------
__global__ __launch_bounds__(128, 3) void k_gemm1(
    const float* __restrict__ x, const float* __restrict__ W1,
    const float* __restrict__ a_s, const float* __restrict__ a_d,
    unsigned* __restrict__ h1b, float* __restrict__ as1, float* __restrict__ ad1)
{
    __shared__ float sW[32 * 128];    // 16 KB (one k-chunk of W)
    __shared__ float sx[64 * 32];     // 8 KB (64 nodes x 32 k, swizzled)
    float4* sW4 = (float4*)sW;
    float4* sx4 = (float4*)sx;
    const float4* x4  = (const float4*)x;
    const float4* W14 = (const float4*)W1;
    const int tid = threadIdx.x;
    const int cg = tid & 15;          // channels 8cg..8cg+7
    const int ng = tid >> 4;          // 0..7 -> nodes 8ng..8ng+7
    const int axor = ng & 7;
    const int n0 = blockIdx.x * 64;

    float4 acc[8][2];
    #pragma unroll
    for (int m = 0; m < 8; m++) { acc[m][0] = make_float4(0,0,0,0); acc[m][1] = make_float4(0,0,0,0); }

    // Prefetch chunk 0 into registers.
    float4 pw[8], px[4];
    #pragma unroll
    for (int j = 0; j < 8; j++) pw[j] = W14[tid + 128 * j];
    #pragma unroll
    for (int j = 0; j < 4; j++) {
        const int idx = tid + 128 * j;
        const int node = idx >> 3, q = idx & 7;
        const int n = n0 + node;
        px[j] = (n < N_NODES) ? x4[n * 32 + q] : make_float4(0,0,0,0);
    }

    for (int c = 0; c < 4; c++) {     // k-chunks of 32
        __syncthreads();
        // Commit prefetched chunk c to LDS.
        #pragma unroll
        for (int j = 0; j < 8; j++) {
            const int idx = tid + 128 * j;
            const int k = idx >> 5, f = idx & 31;
            sW4[k * 32 + ((f & 1) << 4) + (f >> 1)] = pw[j];
        }
        #pragma unroll
        for (int j = 0; j < 4; j++) {
            const int idx = tid + 128 * j;
            const int node = idx >> 3, q = idx & 7;
            sx4[node * 8 + (q ^ ((node >> 3) & 7))] = px[j];
        }
        __syncthreads();
        // Issue chunk c+1's global loads (overlap with compute below).
        if (c < 3) {
            #pragma unroll
            for (int j = 0; j < 8; j++) pw[j] = W14[(c + 1) * 1024 + tid + 128 * j];
            #pragma unroll
            for (int j = 0; j < 4; j++) {
                const int idx = tid + 128 * j;
                const int node = idx >> 3, q = idx & 7;
                const int n = n0 + node;
                px[j] = (n < N_NODES) ? x4[n * 32 + (c + 1) * 8 + q] : make_float4(0,0,0,0);
            }
        }
        #pragma unroll 2
        for (int k4 = 0; k4 < 8; k4++) {
            float4 w0[4], w1[4];
            #pragma unroll
            for (int ks = 0; ks < 4; ks++) {
                w0[ks] = sW4[(4 * k4 + ks) * 32 + cg];
                w1[ks] = sW4[(4 * k4 + ks) * 32 + 16 + cg];
            }
            float4 xv[8];
            #pragma unroll
            for (int m = 0; m < 8; m++) xv[m] = sx4[(8 * ng + m) * 8 + (k4 ^ axor)];
            #pragma unroll
            for (int m = 0; m < 8; m++) {
                const float4 xm = xv[m];
                #define FMA8(S, KS) \
                    acc[m][0].x = fmaf(S, w0[KS].x, acc[m][0].x); \
                    acc[m][0].y = fmaf(S, w0[KS].y, acc[m][0].y); \
                    acc[m][0].z = fmaf(S, w0[KS].z, acc[m][0].z); \
                    acc[m][0].w = fmaf(S, w0[KS].w, acc[m][0].w); \
                    acc[m][1].x = fmaf(S, w1[KS].x, acc[m][1].x); \
                    acc[m][1].y = fmaf(S, w1[KS].y, acc[m][1].y); \
                    acc[m][1].z = fmaf(S, w1[KS].z, acc[m][1].z); \
                    acc[m][1].w = fmaf(S, w1[KS].w, acc[m][1].w);
                FMA8(xm.x, 0) FMA8(xm.y, 1) FMA8(xm.z, 2) FMA8(xm.w, 3)
                #undef FMA8
            }
        }
    }

    // Epilogue: bf16 pack + per-head logits.
    const float4 as_a = ((const float4*)a_s)[2 * cg], as_b = ((const float4*)a_s)[2 * cg + 1];
    const float4 ad_a = ((const float4*)a_d)[2 * cg], ad_b = ((const float4*)a_d)[2 * cg + 1];
    #pragma unroll
    for (int m = 0; m < 8; m++) {
        const int n = n0 + 8 * ng + m;
        float ps = acc[m][0].x * as_a.x + acc[m][0].y * as_a.y + acc[m][0].z * as_a.z + acc[m][0].w * as_a.w
                 + acc[m][1].x * as_b.x + acc[m][1].y * as_b.y + acc[m][1].z * as_b.z + acc[m][1].w * as_b.w;
        float pd = acc[m][0].x * ad_a.x + acc[m][0].y * ad_a.y + acc[m][0].z * ad_a.z + acc[m][0].w * ad_a.w
                 + acc[m][1].x * ad_b.x + acc[m][1].y * ad_b.y + acc[m][1].z * ad_b.z + acc[m][1].w * ad_b.w;
        ps += __shfl_xor(ps, 1); ps += __shfl_xor(ps, 2);
        pd += __shfl_xor(pd, 1); pd += __shfl_xor(pd, 2);
        if (n < N_NODES) {
            uint4 pk;
            pk.x = f2bf(acc[m][0].x) | (f2bf(acc[m][0].y) << 16);
            pk.y = f2bf(acc[m][0].z) | (f2bf(acc[m][0].w) << 16);
            pk.z = f2bf(acc[m][1].x) | (f2bf(acc[m][1].y) << 16);
            pk.w = f2bf(acc[m][1].z) | (f2bf(acc[m][1].w) << 16);
            ((uint4*)h1b)[n * 16 + cg] = pk;
            if ((cg & 3) == 0) {
                as1[n * 4 + (cg >> 2)] = ps;
                ad1[n * 4 + (cg >> 2)] = pd;
            }
        }
    }
}

// ---------------------------------------------------------------------------
// Aggregation layer 1: 16 threads/node, 8 channels each. (unchanged)
// ---------------------------------------------------------------------------
__global__ __launch_bounds__(256) void k_aggr1(
    const int* __restrict__ rowptr, const int* __restrict__ csr_src,
    const float* __restrict__ as1, const float* __restrict__ ad1,
    const uint4* __restrict__ h1u4, float* __restrict__ acc1)
{
    const int d  = blockIdx.x * 16 + (threadIdx.x >> 4);
    const int c8 = threadIdx.x & 15;
    const int hd = c8 >> 2;
    const int r0 = rowptr[d], r1 = rowptr[d + 1];
    const float adv = ad1[d * 4 + hd];
    float den = 0.f;
    float acc[8];
    #pragma unroll
    for (int m = 0; m < 8; m++) acc[m] = 0.f;
    int i = r0;
    for (; i + 2 <= r1; i += 2) {
        const int s0 = csr_src[i], s1 = csr_src[i + 1];
        const float e0 = as1[s0 * 4 + hd], e1 = as1[s1 * 4 + hd];
        const uint4 u0 = h1u4[s0 * 16 + c8];
        const uint4 u1 = h1u4[s1 * 16 + c8];
        const float w0 = expf(lrelu(e0 + adv));
        const float w1 = expf(lrelu(e1 + adv));
        den += w0 + w1;
        acc[0] = fmaf(bflo(u0.x), w0, acc[0]); acc[1] = fmaf(bfhi(u0.x), w0, acc[1]);
        acc[2] = fmaf(bflo(u0.y), w0, acc[2]); acc[3] = fmaf(bfhi(u0.y), w0, acc[3]);
        acc[4] = fmaf(bflo(u0.z), w0, acc[4]); acc[5] = fmaf(bfhi(u0.z), w0, acc[5]);
        acc[6] = fmaf(bflo(u0.w), w0, acc[6]); acc[7] = fmaf(bfhi(u0.w), w0, acc[7]);
        acc[0] = fmaf(bflo(u1.x), w1, acc[0]); acc[1] = fmaf(bfhi(u1.x), w1, acc[1]);
        acc[2] = fmaf(bflo(u1.y), w1, acc[2]); acc[3] = fmaf(bfhi(u1.y), w1, acc[3]);
        acc[4] = fmaf(bflo(u1.z), w1, acc[4]); acc[5] = fmaf(bfhi(u1.z), w1, acc[5]);
        acc[6] = fmaf(bflo(u1.w), w1, acc[6]); acc[7] = fmaf(bfhi(u1.w), w1, acc[7]);
    }
    if (i < r1) {
        const int s = csr_src[i];
        const float w = expf(lrelu(as1[s * 4 + hd] + adv));
        const uint4 u = h1u4[s * 16 + c8];
        den += w;
        acc[0] = fmaf(bflo(u.x), w, acc[0]); acc[1] = fmaf(bfhi(u.x), w, acc[1]);
        acc[2] = fmaf(bflo(u.y), w, acc[2]); acc[3] = fmaf(bfhi(u.y), w, acc[3]);
        acc[4] = fmaf(bflo(u.z), w, acc[4]); acc[5] = fmaf(bfhi(u.z), w, acc[5]);
        acc[6] = fmaf(bflo(u.w), w, acc[6]); acc[7] = fmaf(bfhi(u.w), w, acc[7]);
    }
    const float inv = 1.f / (den + 1e-16f);
    float4 o0 = make_float4(acc[0] * inv, acc[1] * inv, acc[2] * inv, acc[3] * inv);
    float4 o1 = make_float4(acc[4] * inv, acc[5] * inv, acc[6] * inv, acc[7] * inv);
    ((float4*)acc1)[d * 32 + 2 * c8 + 0] = o0;
    ((float4*)acc1)[d * 32 + 2 * c8 + 1] = o1;
}

// ---------------------------------------------------------------------------
// K4: hE = elu(acc1+b1); h2 = hE @ W2 [N,64] -> bf16 table + fp32 logits.
// 64 nodes/block, 128 threads, 782 blocks; thread = 4 nodes x 8 ch;
// 4 k-chunks of 32; register double-buffered staging like k_gemm1.
// ---------------------------------------------------------------------------
__global__ __launch_bounds__(128, 3) void k_layer2(
    const float* __restrict__ acc1, const float* __restrict__ b1,
    const float* __restrict__ W2, const float* __restrict__ a_s2, const float* __restrict__ a_d2,
    unsigned* __restrict__ h2b, float* __restrict__ as2, float* __restrict__ ad2)
{
    __shared__ float sW[32 * 64];     // 8 KB (one k-chunk of W2)
    __shared__ float sx[64 * 32];     // 8 KB (64 nodes x 32 k, swizzled)
    float4* sW4 = (float4*)sW;
    float4* sx4 = (float4*)sx;
    const float4* a14 = (const float4*)acc1;
    const float4* W24 = (const float4*)W2;
    const float4* b14 = (const float4*)b1;
    const int tid = threadIdx.x;
    const int cg = tid & 7;           // channels 8cg..8cg+7
    const int ng = tid >> 3;          // 0..15 -> nodes 4ng..4ng+3
    const int axor = ng & 7;          // = (node>>2)&7 for node=4ng+m (m<4)
    const int n0 = blockIdx.x * 64;

    float4 acc[4][2];
    #pragma unroll
    for (int m = 0; m < 4; m++) { acc[m][0] = make_float4(0,0,0,0); acc[m][1] = make_float4(0,0,0,0); }

    // Prefetch chunk 0.
    float4 pw[4], px[4];
    #pragma unroll
    for (int j = 0; j < 4; j++) pw[j] = W24[tid + 128 * j];
    #pragma unroll
    for (int j = 0; j < 4; j++) {
        const int idx = tid + 128 * j;
        const int node = idx >> 3, q = idx & 7;
        const int n = n0 + node;
        px[j] = (n < N_NODES) ? a14[n * 32 + q] : make_float4(0,0,0,0);
    }

    for (int c = 0; c < 4; c++) {
        __syncthreads();
        #pragma unroll
        for (int j = 0; j < 4; j++) {
            const int idx = tid + 128 * j;
            const int k = idx >> 4, f = idx & 15;
            sW4[k * 16 + ((f & 1) << 3) + (f >> 1)] = pw[j];
        }
        #pragma unroll
        for (int j = 0; j < 4; j++) {
            const int idx = tid + 128 * j;
            const int node = idx >> 3, q = idx & 7;
            float4 v = px[j];
            const float4 bb = b14[c * 8 + q];
            v.x = eluf(v.x + bb.x);
            v.y = eluf(v.y + bb.y);
            v.z = eluf(v.z + bb.z);
            v.w = eluf(v.w + bb.w);
            sx4[node * 8 + (q ^ ((node >> 2) & 7))] = v;
        }
        __syncthreads();
        if (c < 3) {
            #pragma unroll
            for (int j = 0; j < 4; j++) pw[j] = W24[(c + 1) * 512 + tid + 128 * j];
            #pragma unroll
            for (int j = 0; j < 4; j++) {
                const int idx = tid + 128 * j;
                const int node = idx >> 3, q = idx & 7;
                const int n = n0 + node;
                px[j] = (n < N_NODES) ? a14[n * 32 + (c + 1) * 8 + q] : make_float4(0,0,0,0);
            }
        }
        #pragma unroll 2
        for (int k4 = 0; k4 < 8; k4++) {
            float4 w0[4], w1[4];
            #pragma unroll
            for (int ks = 0; ks < 4; ks++) {
                w0[ks] = sW4[(4 * k4 + ks) * 16 + cg];
                w1[ks] = sW4[(4 * k4 + ks) * 16 + 8 + cg];
            }
            float4 xv[4];
            #pragma unroll
            for (int m = 0; m < 4; m++) {
                const int node = 4 * ng + m;
                xv[m] = sx4[node * 8 + (k4 ^ axor)];
            }
            #pragma unroll
            for (int m = 0; m < 4; m++) {
                const float4 xm = xv[m];
                #define FMA8(S, KS) \
                    acc[m][0].x = fmaf(S, w0[KS].x, acc[m][0].x); \
                    acc[m][0].y = fmaf(S, w0[KS].y, acc[m][0].y); \
                    acc[m][0].z = fmaf(S, w0[KS].z, acc[m][0].z); \
                    acc[m][0].w = fmaf(S, w0[KS].w, acc[m][0].w); \
                    acc[m][1].x = fmaf(S, w1[KS].x, acc[m][1].x); \
                    acc[m][1].y = fmaf(S, w1[KS].y, acc[m][1].y); \
                    acc[m][1].z = fmaf(S, w1[KS].z, acc[m][1].z); \
                    acc[m][1].w = fmaf(S, w1[KS].w, acc[m][1].w);
                FMA8(xm.x, 0) FMA8(xm.y, 1) FMA8(xm.z, 2) FMA8(xm.w, 3)
                #undef FMA8
            }
        }
    }

    // Epilogue: bf16 pack + single-head logits (reduce over 8 cg lanes).
    const float4 as_a = ((const float4*)a_s2)[2 * cg], as_b = ((const float4*)a_s2)[2 * cg + 1];
    const float4 ad_a = ((const float4*)a_d2)[2 * cg], ad_b = ((const float4*)a_d2)[2 * cg + 1];
    #pragma unroll
    for (int m = 0; m < 4; m++) {
        const int n = n0 + 4 * ng + m;
        float ps = acc[m][0].x * as_a.x + acc[m][0].y * as_a.y + acc[m][0].z * as_a.z + acc[m][0].w * as_a.w
                 + acc[m][1].x * as_b.x + acc[m][1].y * as_b.y + acc[m][1].z * as_b.z + acc[m][1].w * as_b.w;
        float pd = acc[m][0].x * ad_a.x + acc[m][0].y * ad_a.y + acc[m][0].z * ad_a.z + acc[m][0].w * ad_a.w
                 + acc[m][1].x * ad_b.x + acc[m][1].y * ad_b.y + acc[m][1].z * ad_b.z + acc[m][1].w * ad_b.w;
        ps += __shfl_xor(ps, 1); ps += __shfl_xor(ps, 2); ps += __shfl_xor(ps, 4);
        pd += __shfl_xor(pd, 1); pd += __shfl_xor(pd, 2); pd += __shfl_xor(pd, 4);
        if (n < N_NODES) {
            uint4 pk;
            pk.x = f2bf(acc[m][0].x) | (f2bf(acc[m][0].y) << 16);
            pk.y = f2bf(acc[m][0].z) | (f2bf(acc[m][0].w) << 16);
            pk.z = f2bf(acc[m][1].x) | (f2bf(acc[m][1].y) << 16);
            pk.w = f2bf(acc[m][1].z) | (f2bf(acc[m][1].w) << 16);
            ((uint4*)h2b)[n * 8 + cg] = pk;
            if (cg == 0) { as2[n] = ps; ad2[n] = pd; }
        }
    }
}

// ---------------------------------------------------------------------------
// Aggregation layer 2: 8 threads/node, 8 channels each. (unchanged)
// ---------------------------------------------------------------------------
__global__ __launch_bounds__(256) void k_aggr2(
    const int* __restrict__ rowptr, const int* __restrict__ csr_src,
    const float* __restrict__ as2, const float* __restrict__ ad2,
    const uint4* __restrict__ h2u4, float* __restrict__ acc2)
{
    const int d  = blockIdx.x * 32 + (threadIdx.x >> 3);
    const int c8 = threadIdx.x & 7;
    if (d >= N_NODES) return;
    const int r0 = rowptr[d], r1 = rowptr[d + 1];
    const float adv = ad2[d];
    float den = 0.f;
    float acc[8];
    #pragma unroll
    for (int m = 0; m < 8; m++) acc[m] = 0.f;
    int i = r0;
    for (; i + 2 <= r1; i += 2) {
        const int s0 = csr_src[i], s1 = csr_src[i + 1];
        const float e0 = as2[s0], e1 = as2[s1];
        const uint4 u0 = h2u4[s0 * 8 + c8];
        const uint4 u1 = h2u4[s1 * 8 + c8];
        const float w0 = expf(lrelu(e0 + adv));
        const float w1 = expf(lrelu(e1 + adv));
        den += w0 + w1;
        acc[0] = fmaf(bflo(u0.x), w0, acc[0]); acc[1] = fmaf(bfhi(u0.x), w0, acc[1]);
        acc[2] = fmaf(bflo(u0.y), w0, acc[2]); acc[3] = fmaf(bfhi(u0.y), w0, acc[3]);
        acc[4] = fmaf(bflo(u0.z), w0, acc[4]); acc[5] = fmaf(bfhi(u0.z), w0, acc[5]);
        acc[6] = fmaf(bflo(u0.w), w0, acc[6]); acc[7] = fmaf(bfhi(u0.w), w0, acc[7]);
        acc[0] = fmaf(bflo(u1.x), w1, acc[0]); acc[1] = fmaf(bfhi(u1.x), w1, acc[1]);
        acc[2] = fmaf(bflo(u1.y), w1, acc[2]); acc[3] = fmaf(bfhi(u1.y), w1, acc[3]);
        acc[4] = fmaf(bflo(u1.z), w1, acc[4]); acc[5] = fmaf(bfhi(u1.z), w1, acc[5]);
        acc[6] = fmaf(bflo(u1.w), w1, acc[6]); acc[7] = fmaf(bfhi(u1.w), w1, acc[7]);
    }
    if (i < r1) {
        const int s = csr_src[i];
        const float w = expf(lrelu(as2[s] + adv));
        const uint4 u = h2u4[s * 8 + c8];
        den += w;
        acc[0] = fmaf(bflo(u.x), w, acc[0]); acc[1] = fmaf(bfhi(u.x), w, acc[1]);
        acc[2] = fmaf(bflo(u.y), w, acc[2]); acc[3] = fmaf(bfhi(u.y), w, acc[3]);
        acc[4] = fmaf(bflo(u.z), w, acc[4]); acc[5] = fmaf(bfhi(u.z), w, acc[5]);
        acc[6] = fmaf(bflo(u.w), w, acc[6]); acc[7] = fmaf(bfhi(u.w), w, acc[7]);
    }
    const float inv = 1.f / (den + 1e-16f);
    float4 o0 = make_float4(acc[0] * inv, acc[1] * inv, acc[2] * inv, acc[3] * inv);
    float4 o1 = make_float4(acc[4] * inv, acc[5] * inv, acc[6] * inv, acc[7] * inv);
    ((float4*)acc2)[d * 16 + 2 * c8 + 0] = o0;
    ((float4*)acc2)[d * 16 + 2 * c8 + 1] = o1;
}

// ---------------------------------------------------------------------------
// K7: o = elu(acc2+b2); p = relu(o@pw1+pb1); out = p@pw2+pb2. (unchanged)
// ---------------------------------------------------------------------------
__global__ __launch_bounds__(256, 2) void k_out(
    const float* __restrict__ acc2, const float* __restrict__ b2,
    const float* __restrict__ pw1, const float* __restrict__ pb1,
    const float* __restrict__ pw2, const float* __restrict__ pb2,
    float* __restrict__ out)
{
    __shared__ float s1[64 * 64];
    __shared__ float s2[64 * 64];
    __shared__ float so[64][68];
    __shared__ float sp[64][68];
    const int tid = threadIdx.x;
    for (int i = tid; i < 1024; i += 256) {
        ((float4*)s1)[i] = ((const float4*)pw1)[i];
        ((float4*)s2)[i] = ((const float4*)pw2)[i];
    }
    const int cg = tid & 15;
    const int ng = tid >> 4;
    const float4 pb1_4 = ((const float4*)pb1)[cg];
    const float4 pb2_4 = ((const float4*)pb2)[cg];
    const int nGroups = (N_NODES + 63) / 64;   // 782
    for (int g = blockIdx.x; g < nGroups; g += gridDim.x) {
        const int n0 = g * 64;
        __syncthreads();
        #pragma unroll
        for (int j = 0; j < 4; j++) {
            const int i = tid + 256 * j;
            const int node = i >> 4, quad = i & 15;
            const int n = n0 + node;
            float4 v = make_float4(0.f, 0.f, 0.f, 0.f);
            if (n < N_NODES) {
                v = ((const float4*)acc2)[n * 16 + quad];
                const float4 bb = ((const float4*)b2)[quad];
                v.x = eluf(v.x + bb.x);
                v.y = eluf(v.y + bb.y);
                v.z = eluf(v.z + bb.z);
                v.w = eluf(v.w + bb.w);
            }
            *(float4*)&so[node][4 * quad] = v;
        }
        __syncthreads();
        float4 p[4];
        #pragma unroll
        for (int m = 0; m < 4; m++) p[m] = pb1_4;
        #pragma unroll 8
        for (int k = 0; k < 64; k++) {
            const float4 w = *(const float4*)&s1[k * 64 + 4 * cg];
            #pragma unroll
            for (int m = 0; m < 4; m++) {
                const float xv = so[4 * ng + m][k];
                p[m].x = fmaf(xv, w.x, p[m].x);
                p[m].y = fmaf(xv, w.y, p[m].y);
                p[m].z = fmaf(xv, w.z, p[m].z);
                p[m].w = fmaf(xv, w.w, p[m].w);
            }
        }
        #pragma unroll
        for (int m = 0; m < 4; m++) {
            p[m].x = fmaxf(p[m].x, 0.f); p[m].y = fmaxf(p[m].y, 0.f);
            p[m].z = fmaxf(p[m].z, 0.f); p[m].w = fmaxf(p[m].w, 0.f);
            *(float4*)&sp[4 * ng + m][4 * cg] = p[m];
        }
        __syncthreads();
        float4 o[4];
        #pragma unroll
        for (int m = 0; m < 4; m++) o[m] = pb2_4;
        #pragma unroll 8
        for (int k = 0; k < 64; k++) {
            const float4 w = *(const float4*)&s2[k * 64 + 4 * cg];
            #pragma unroll
            for (int m = 0; m < 4; m++) {
                const float xv = sp[4 * ng + m][k];
                o[m].x = fmaf(xv, w.x, o[m].x);
                o[m].y = fmaf(xv, w.y, o[m].y);
                o[m].z = fmaf(xv, w.z, o[m].z);
                o[m].w = fmaf(xv, w.w, o[m].w);
            }
        }
        #pragma unroll
        for (int m = 0; m < 4; m++) {
            const int n = n0 + 4 * ng + m;
            if (n < N_NODES) ((float4*)out)[n * 16 + cg] = o[m];
        }
    }
}

// ---------------------------------------------------------------------------
extern "C" void kernel_launch(void* const* d_in, const int* in_sizes, int n_in,
                              void* d_out, int out_size, void* d_ws, size_t ws_size,
                              hipStream_t stream)
{
    const float* x      = (const float*)d_in[0];
    const int*   ei     = (const int*)d_in[1];   // [2, E] int32
    const int*   src    = ei;
    const int*   dst    = ei + N_EDGES;
    const float* W1     = (const float*)d_in[2];
    const float* a_src1 = (const float*)d_in[3];
    const float* a_dst1 = (const float*)d_in[4];
    const float* b1     = (const float*)d_in[5];
    const float* W2     = (const float*)d_in[6];
    const float* a_src2 = (const float*)d_in[7];
    const float* a_dst2 = (const float*)d_in[8];
    const float* b2     = (const float*)d_in[9];
    const float* pw1    = (const float*)d_in[10];
    const float* pb1    = (const float*)d_in[11];
    const float* pw2    = (const float*)d_in[12];
    const float* pb2    = (const float*)d_in[13];

    // Workspace layout. part first (8B align from d_ws base).
    uint2* part  = (uint2*)d_ws;          // ET uint2
    int* ibase   = (int*)(part + ET);
    int* rowptr  = ibase;                 // 50,001
    int* C       = rowptr + 50001;        // NBUCK*NBLK = 200,192
    int* Cs      = C + 200192;            // 200,192
    int* bsum2   = Cs + 200192;           // 782
    int* boff2   = bsum2 + 782;           // 783 (+2 pad -> 785)
    int* csr_src = boff2 + 785;           // 850,000
    unsigned* h1b = (unsigned*)(csr_src + 850000);  // N*64 uints (bf16 x2)
    unsigned* h2b = h1b + 3200000;                  // N*32 uints
    float* fws   = (float*)(h2b + 1600000);
    float* as1   = fws;                   // N*4
    float* ad1   = as1 + 200000;          // N*4
    float* acc1  = ad1 + 200000;          // N*128
    float* as2   = acc1 + 6400000;        // N
    float* ad2   = as2 + 50000;           // N
    float* acc2  = ad2 + 50000;           // N*64

    // CSR build — atomic-free radix partition (reused by both layers).
    k_count<<<NBLK, 256, 0, stream>>>(dst, C);
    k_bsumA<<<NBUCK, 256, 0, stream>>>(C, bsum2);
    k_bscanB<<<1, 1024, 0, stream>>>(bsum2, boff2);
    k_cscanC<<<NBUCK, 256, 0, stream>>>(C, boff2, Cs);
    k_part2<<<NBLK, 256, 0, stream>>>(src, dst, Cs, part);
    k_scat2<<<NBUCK, 256, 0, stream>>>(boff2, part, rowptr, csr_src);

    // Layer 1
    k_gemm1<<<(N_NODES + 63) / 64, 128, 0, stream>>>(x, W1, a_src1, a_dst1, h1b, as1, ad1);
    k_aggr1<<<N_NODES / 16, 256, 0, stream>>>(rowptr, csr_src, as1, ad1,
                                              (const uint4*)h1b, acc1);

    // Layer 2
    k_layer2<<<(N_NODES + 63) / 64, 128, 0, stream>>>(acc1, b1, W2, a_src2, a_dst2, h2b, as2, ad2);
    k_aggr2<<<(N_NODES + 31) / 32, 256, 0, stream>>>(rowptr, csr_src, as2, ad2,
                                                     (const uint4*)h2b, acc2);

    // Output MLP
    k_out<<<782, 256, 0, stream>>>(acc2, b2, pw1, pb1, pw2, pb2, (float*)d_out);
}

// Round 13
// 258.585 us; speedup vs baseline: 1.1052x; 1.1052x over previous
//
#include <hip/hip_runtime.h>
#include <math.h>

// Problem constants (from reference)
#define N_NODES 50000
#define N_EDGES 800000
#define ET (N_EDGES + N_NODES)   // edges + self loops = 850000
#define IN_DIM 128
#define HID 128
#define OUT_DIM 64
#define BW 64                              // bucket width (dst nodes)
#define NBUCK ((N_NODES + BW - 1) / BW)    // 782 buckets
#define NBLK 256                           // partition blocks
#define EPB 3328                           // edges per partition block (13*256)

typedef __attribute__((ext_vector_type(8))) short bf16x8;
typedef __attribute__((ext_vector_type(4))) float f32x4;

__device__ __forceinline__ float lrelu(float x){ return x >= 0.f ? x : 0.2f * x; }
__device__ __forceinline__ float eluf(float x){ return x > 0.f ? x : expm1f(x); }
// RNE float->bf16 (finite inputs)
__device__ __forceinline__ unsigned f2bf(float f){
    unsigned u = __float_as_uint(f);
    return (u + 0x7fffu + ((u >> 16) & 1u)) >> 16;
}
__device__ __forceinline__ float bflo(unsigned u){ return __uint_as_float(u << 16); }
__device__ __forceinline__ float bfhi(unsigned u){ return __uint_as_float(u & 0xffff0000u); }

// ---------------------------------------------------------------------------
// CSR build, atomic-free radix style (unchanged).
// ---------------------------------------------------------------------------
__global__ __launch_bounds__(256) void k_count(const int* __restrict__ dst, int* __restrict__ C)
{
    __shared__ int cnt[NBUCK];
    const int tid = threadIdx.x, blk = blockIdx.x;
    for (int i = tid; i < NBUCK; i += 256) cnt[i] = 0;
    __syncthreads();
    #pragma unroll
    for (int j = 0; j < EPB / 256; j++) {
        const int e = blk * EPB + j * 256 + tid;
        if (e < ET) {
            const int d = (e < N_EDGES) ? dst[e] : (e - N_EDGES);
            atomicAdd(&cnt[d >> 6], 1);
        }
    }
    __syncthreads();
    for (int b = tid; b < NBUCK; b += 256) C[b * NBLK + blk] = cnt[b];
}

__global__ __launch_bounds__(256) void k_bsumA(const int* __restrict__ C, int* __restrict__ bsum2)
{
    __shared__ int red[4];
    int v = C[blockIdx.x * NBLK + threadIdx.x];
    #pragma unroll
    for (int off = 32; off > 0; off >>= 1) v += __shfl_down(v, off);
    if ((threadIdx.x & 63) == 0) red[threadIdx.x >> 6] = v;
    __syncthreads();
    if (threadIdx.x == 0) bsum2[blockIdx.x] = red[0] + red[1] + red[2] + red[3];
}

__global__ __launch_bounds__(1024) void k_bscanB(const int* __restrict__ bsum2, int* __restrict__ boff2)
{
    __shared__ int part[1024];
    const int t = threadIdx.x;
    int v = (t < NBUCK) ? bsum2[t] : 0;
    part[t] = v;
    __syncthreads();
    #pragma unroll
    for (int d = 1; d < 1024; d <<= 1) {
        int add = (t >= d) ? part[t - d] : 0;
        __syncthreads();
        part[t] += add;
        __syncthreads();
    }
    if (t < NBUCK) boff2[t] = part[t] - v;   // exclusive
    if (t == 0) boff2[NBUCK] = ET;
}

__global__ __launch_bounds__(256) void k_cscanC(const int* __restrict__ C,
                                                const int* __restrict__ boff2,
                                                int* __restrict__ Cs)
{
    __shared__ int part[256];
    const int t = threadIdx.x, b = blockIdx.x;
    int v = C[b * NBLK + t];
    part[t] = v;
    __syncthreads();
    #pragma unroll
    for (int d = 1; d < 256; d <<= 1) {
        int add = (t >= d) ? part[t - d] : 0;
        __syncthreads();
        part[t] += add;
        __syncthreads();
    }
    Cs[b * NBLK + t] = boff2[b] + part[t] - v;
}

__global__ __launch_bounds__(256) void k_part2(const int* __restrict__ src,
                                               const int* __restrict__ dst,
                                               const int* __restrict__ Cs,
                                               uint2* __restrict__ part)
{
    __shared__ int base[NBUCK];
    __shared__ int cnt[NBUCK];
    const int tid = threadIdx.x, blk = blockIdx.x;
    for (int b = tid; b < NBUCK; b += 256) { base[b] = Cs[b * NBLK + blk]; cnt[b] = 0; }
    __syncthreads();
    #pragma unroll
    for (int j = 0; j < EPB / 256; j++) {
        const int e = blk * EPB + j * 256 + tid;
        if (e < ET) {
            int s, d;
            if (e < N_EDGES) { s = src[e]; d = dst[e]; } else { s = d = e - N_EDGES; }
            const int b = d >> 6;
            const int r = atomicAdd(&cnt[b], 1);
            part[base[b] + r] = make_uint2((unsigned)d, (unsigned)s);
        }
    }
}

__global__ __launch_bounds__(256) void k_scat2(const int* __restrict__ boff2,
                                               const uint2* __restrict__ part,
                                               int* __restrict__ rowptr,
                                               int* __restrict__ csr_src)
{
    __shared__ int cnt64[BW];
    __shared__ int nbase[BW];
    const int b = blockIdx.x, tid = threadIdx.x;
    const int n0 = b * BW;
    const int lo = boff2[b], hi = boff2[b + 1];
    if (tid < BW) cnt64[tid] = 0;
    __syncthreads();
    for (int i = lo + tid; i < hi; i += 256) {
        atomicAdd(&cnt64[part[i].x & (BW - 1)], 1);
    }
    __syncthreads();
    if (tid < BW) {
        int v = cnt64[tid];
        int incl = v;
        #pragma unroll
        for (int off = 1; off < 64; off <<= 1) {
            int t2 = __shfl_up(incl, off);
            if (tid >= off) incl += t2;
        }
        const int excl = incl - v;
        nbase[tid] = excl;
        const int n = n0 + tid;
        if (n < N_NODES) rowptr[n] = lo + excl;
        cnt64[tid] = 0;
    }
    if (b == 0 && tid == 0) rowptr[N_NODES] = ET;
    __syncthreads();
    for (int i = lo + tid; i < hi; i += 256) {
        const uint2 p = part[i];
        const int dn = (int)p.x & (BW - 1);
        const int r = atomicAdd(&cnt64[dn], 1);
        csr_src[lo + nbase[dn] + r] = (int)p.y;
    }
}

// ---------------------------------------------------------------------------
// K1 (MFMA): h1 = x @ W1 [N,128] -> bf16 table + fp32 logits.
// 64 nodes/block, 256 threads (4 waves), 782 blocks. Wave = one 16-node
// M-tile x full N=128 (8 accumulators), mfma_f32_16x16x32_bf16, K=128 in 4
// steps. W1^T and x converted to bf16 in LDS ONCE (no k-chunk re-staging,
// single barrier). Row stride 68 uints keeps b128 frags 16B-aligned and
// bank-conflict-free (2-way max).
// Layouts (HW-verified per guide): A[m=lane&15][k=quad*8+j];
// B from [n][k]-stored LDS (the m92 "B^T input" pattern);
// C/D: col=lane&15, row=quad*4+reg.
// ---------------------------------------------------------------------------
__global__ __launch_bounds__(256, 2) void k_gemm1(
    const float* __restrict__ x, const float* __restrict__ W1,
    const float* __restrict__ a_s, const float* __restrict__ a_d,
    unsigned* __restrict__ h1b, float* __restrict__ as1, float* __restrict__ ad1)
{
    __shared__ unsigned sWt[128 * 68];   // W^T bf16 pairs: [n][kp], 34.8 KB
    __shared__ unsigned sxb[64 * 68];    // x   bf16 pairs: [node][kp], 17.4 KB
    const int tid = threadIdx.x;
    const int wave = tid >> 6;           // 0..3 -> M-tile (16 nodes)
    const int lane = tid & 63;
    const int ll   = lane & 15;
    const int quad = lane >> 4;
    const int n0 = blockIdx.x * 64;

    // Stage W^T: 8192 uints. thread idx: n = idx&127 (coalesced W1 reads), kp = idx>>7.
    for (int idx = tid; idx < 8192; idx += 256) {
        const int n = idx & 127, kp = idx >> 7;
        const float w0 = W1[(2 * kp) * 128 + n];
        const float w1 = W1[(2 * kp + 1) * 128 + n];
        sWt[n * 68 + kp] = f2bf(w0) | (f2bf(w1) << 16);
    }
    // Stage x: 4096 uints. node = idx>>6, kp = idx&63 (coalesced x reads).
    for (int idx = tid; idx < 4096; idx += 256) {
        const int node = idx >> 6, kp = idx & 63;
        const int n = n0 + node;
        unsigned pk = 0;
        if (n < N_NODES) {
            const float x0 = x[n * 128 + 2 * kp];
            const float x1 = x[n * 128 + 2 * kp + 1];
            pk = f2bf(x0) | (f2bf(x1) << 16);
        }
        sxb[node * 68 + kp] = pk;
    }
    __syncthreads();

    f32x4 acc[8];
    #pragma unroll
    for (int t = 0; t < 8; t++) acc[t] = (f32x4){0.f, 0.f, 0.f, 0.f};

    #pragma unroll
    for (int kk = 0; kk < 4; kk++) {
        const int kpo = 16 * kk + 4 * quad;   // k base = 32kk + 8*quad (in bf16), /2 pairs
        const bf16x8 a = *(const bf16x8*)&sxb[(16 * wave + ll) * 68 + kpo];
        #pragma unroll
        for (int t = 0; t < 8; t++) {
            const bf16x8 b = *(const bf16x8*)&sWt[(16 * t + ll) * 68 + kpo];
            acc[t] = __builtin_amdgcn_mfma_f32_16x16x32_bf16(a, b, acc[t], 0, 0, 0);
        }
    }

    // Epilogue. Lane holds cols c = 16t+ll, rows 4*quad+r of the wave's M-tile.
    float as_v[8], ad_v[8];
    #pragma unroll
    for (int t = 0; t < 8; t++) { as_v[t] = a_s[16 * t + ll]; ad_v[t] = a_d[16 * t + ll]; }
    unsigned short* h1u = (unsigned short*)h1b;
    #pragma unroll
    for (int r = 0; r < 4; r++) {
        const int n = n0 + 16 * wave + 4 * quad + r;
        // head h <- tiles 2h, 2h+1 (cols 16t+ll, ll<16 -> head = t>>1)
        float ps0 = acc[0][r] * as_v[0] + acc[1][r] * as_v[1];
        float ps1 = acc[2][r] * as_v[2] + acc[3][r] * as_v[3];
        float ps2 = acc[4][r] * as_v[4] + acc[5][r] * as_v[5];
        float ps3 = acc[6][r] * as_v[6] + acc[7][r] * as_v[7];
        float pd0 = acc[0][r] * ad_v[0] + acc[1][r] * ad_v[1];
        float pd1 = acc[2][r] * ad_v[2] + acc[3][r] * ad_v[3];
        float pd2 = acc[4][r] * ad_v[4] + acc[5][r] * ad_v[5];
        float pd3 = acc[6][r] * ad_v[6] + acc[7][r] * ad_v[7];
        #pragma unroll
        for (int off = 1; off < 16; off <<= 1) {
            ps0 += __shfl_xor(ps0, off); ps1 += __shfl_xor(ps1, off);
            ps2 += __shfl_xor(ps2, off); ps3 += __shfl_xor(ps3, off);
            pd0 += __shfl_xor(pd0, off); pd1 += __shfl_xor(pd1, off);
            pd2 += __shfl_xor(pd2, off); pd3 += __shfl_xor(pd3, off);
        }
        if (n < N_NODES) {
            #pragma unroll
            for (int t = 0; t < 8; t++)
                h1u[n * 128 + 16 * t + ll] = (unsigned short)f2bf(acc[t][r]);
            if (ll == 0) {
                as1[n * 4 + 0] = ps0; as1[n * 4 + 1] = ps1;
                as1[n * 4 + 2] = ps2; as1[n * 4 + 3] = ps3;
                ad1[n * 4 + 0] = pd0; ad1[n * 4 + 1] = pd1;
                ad1[n * 4 + 2] = pd2; ad1[n * 4 + 3] = pd3;
            }
        }
    }
}

// ---------------------------------------------------------------------------
// Aggregation layer 1: 16 threads/node, 8 channels each. (unchanged)
// ---------------------------------------------------------------------------
__global__ __launch_bounds__(256) void k_aggr1(
    const int* __restrict__ rowptr, const int* __restrict__ csr_src,
    const float* __restrict__ as1, const float* __restrict__ ad1,
    const uint4* __restrict__ h1u4, float* __restrict__ acc1)
{
    const int d  = blockIdx.x * 16 + (threadIdx.x >> 4);
    const int c8 = threadIdx.x & 15;
    const int hd = c8 >> 2;
    const int r0 = rowptr[d], r1 = rowptr[d + 1];
    const float adv = ad1[d * 4 + hd];
    float den = 0.f;
    float acc[8];
    #pragma unroll
    for (int m = 0; m < 8; m++) acc[m] = 0.f;
    int i = r0;
    for (; i + 2 <= r1; i += 2) {
        const int s0 = csr_src[i], s1 = csr_src[i + 1];
        const float e0 = as1[s0 * 4 + hd], e1 = as1[s1 * 4 + hd];
        const uint4 u0 = h1u4[s0 * 16 + c8];
        const uint4 u1 = h1u4[s1 * 16 + c8];
        const float w0 = expf(lrelu(e0 + adv));
        const float w1 = expf(lrelu(e1 + adv));
        den += w0 + w1;
        acc[0] = fmaf(bflo(u0.x), w0, acc[0]); acc[1] = fmaf(bfhi(u0.x), w0, acc[1]);
        acc[2] = fmaf(bflo(u0.y), w0, acc[2]); acc[3] = fmaf(bfhi(u0.y), w0, acc[3]);
        acc[4] = fmaf(bflo(u0.z), w0, acc[4]); acc[5] = fmaf(bfhi(u0.z), w0, acc[5]);
        acc[6] = fmaf(bflo(u0.w), w0, acc[6]); acc[7] = fmaf(bfhi(u0.w), w0, acc[7]);
        acc[0] = fmaf(bflo(u1.x), w1, acc[0]); acc[1] = fmaf(bfhi(u1.x), w1, acc[1]);
        acc[2] = fmaf(bflo(u1.y), w1, acc[2]); acc[3] = fmaf(bfhi(u1.y), w1, acc[3]);
        acc[4] = fmaf(bflo(u1.z), w1, acc[4]); acc[5] = fmaf(bfhi(u1.z), w1, acc[5]);
        acc[6] = fmaf(bflo(u1.w), w1, acc[6]); acc[7] = fmaf(bfhi(u1.w), w1, acc[7]);
    }
    if (i < r1) {
        const int s = csr_src[i];
        const float w = expf(lrelu(as1[s * 4 + hd] + adv));
        const uint4 u = h1u4[s * 16 + c8];
        den += w;
        acc[0] = fmaf(bflo(u.x), w, acc[0]); acc[1] = fmaf(bfhi(u.x), w, acc[1]);
        acc[2] = fmaf(bflo(u.y), w, acc[2]); acc[3] = fmaf(bfhi(u.y), w, acc[3]);
        acc[4] = fmaf(bflo(u.z), w, acc[4]); acc[5] = fmaf(bfhi(u.z), w, acc[5]);
        acc[6] = fmaf(bflo(u.w), w, acc[6]); acc[7] = fmaf(bfhi(u.w), w, acc[7]);
    }
    const float inv = 1.f / (den + 1e-16f);
    float4 o0 = make_float4(acc[0] * inv, acc[1] * inv, acc[2] * inv, acc[3] * inv);
    float4 o1 = make_float4(acc[4] * inv, acc[5] * inv, acc[6] * inv, acc[7] * inv);
    ((float4*)acc1)[d * 32 + 2 * c8 + 0] = o0;
    ((float4*)acc1)[d * 32 + 2 * c8 + 1] = o1;
}

// ---------------------------------------------------------------------------
// K4: hE = elu(acc1+b1); h2 = hE @ W2 [N,64] -> bf16 table + fp32 logits.
// R10 config: 4 nodes x 8 ch per thread, 128 nodes/block, (256,4), 24 KB LDS.
// ---------------------------------------------------------------------------
__global__ __launch_bounds__(256, 4) void k_layer2(
    const float* __restrict__ acc1, const float* __restrict__ b1,
    const float* __restrict__ W2, const float* __restrict__ a_s2, const float* __restrict__ a_d2,
    unsigned* __restrict__ h2b, float* __restrict__ as2, float* __restrict__ ad2)
{
    __shared__ float sW[32 * 64];     // 8 KB (one k-chunk of W2)
    __shared__ float sx[128 * 32];    // 16 KB (128 nodes x 32 k, swizzled)
    float4* sW4 = (float4*)sW;
    float4* sx4 = (float4*)sx;
    const float4* a14 = (const float4*)acc1;
    const float4* W24 = (const float4*)W2;
    const float4* b14 = (const float4*)b1;
    const int tid = threadIdx.x;
    const int cg = tid & 7;           // channels 8cg..8cg+7
    const int ng = tid >> 3;          // node group 0..31 (nodes 4ng..4ng+3)
    const int n0 = blockIdx.x * 128;

    float4 acc[4][2];
    #pragma unroll
    for (int m = 0; m < 4; m++) { acc[m][0] = make_float4(0,0,0,0); acc[m][1] = make_float4(0,0,0,0); }

    for (int c = 0; c < 4; c++) {
        __syncthreads();
        #pragma unroll
        for (int j = 0; j < 2; j++) { // stage W2 chunk: 512 float4
            const int idx = tid + 256 * j;
            float4 v = W24[c * 512 + idx];
            const int k = idx >> 4, f = idx & 15;
            sW4[k * 16 + ((f & 1) << 3) + (f >> 1)] = v;
        }
        #pragma unroll
        for (int j = 0; j < 4; j++) { // stage elu(acc1+b1) chunk: 1024 float4
            const int idx = tid + 256 * j;
            const int node = idx >> 3, q = idx & 7;
            const int n = n0 + node;
            float4 v = make_float4(0,0,0,0);
            if (n < N_NODES) {
                v = a14[n * 32 + c * 8 + q];
                const float4 bb = b14[c * 8 + q];
                v.x = eluf(v.x + bb.x);
                v.y = eluf(v.y + bb.y);
                v.z = eluf(v.z + bb.z);
                v.w = eluf(v.w + bb.w);
            }
            sx4[node * 8 + (q ^ ((node >> 3) & 7))] = v;
        }
        __syncthreads();
        #pragma unroll 2
        for (int k4 = 0; k4 < 8; k4++) {
            float4 w0[4], w1[4];
            #pragma unroll
            for (int ks = 0; ks < 4; ks++) {
                w0[ks] = sW4[(4 * k4 + ks) * 16 + cg];
                w1[ks] = sW4[(4 * k4 + ks) * 16 + 8 + cg];
            }
            float4 xv[4];
            #pragma unroll
            for (int m = 0; m < 4; m++) {
                const int node = 4 * ng + m;
                xv[m] = sx4[node * 8 + (k4 ^ ((node >> 3) & 7))];
            }
            #pragma unroll
            for (int m = 0; m < 4; m++) {
                const float4 xm = xv[m];
                #define FMA8(S, KS) \
                    acc[m][0].x = fmaf(S, w0[KS].x, acc[m][0].x); \
                    acc[m][0].y = fmaf(S, w0[KS].y, acc[m][0].y); \
                    acc[m][0].z = fmaf(S, w0[KS].z, acc[m][0].z); \
                    acc[m][0].w = fmaf(S, w0[KS].w, acc[m][0].w); \
                    acc[m][1].x = fmaf(S, w1[KS].x, acc[m][1].x); \
                    acc[m][1].y = fmaf(S, w1[KS].y, acc[m][1].y); \
                    acc[m][1].z = fmaf(S, w1[KS].z, acc[m][1].z); \
                    acc[m][1].w = fmaf(S, w1[KS].w, acc[m][1].w);
                FMA8(xm.x, 0) FMA8(xm.y, 1) FMA8(xm.z, 2) FMA8(xm.w, 3)
                #undef FMA8
            }
        }
    }

    // Epilogue: bf16 pack + single-head logits (reduce over 8 cg lanes).
    const float4 as_a = ((const float4*)a_s2)[2 * cg], as_b = ((const float4*)a_s2)[2 * cg + 1];
    const float4 ad_a = ((const float4*)a_d2)[2 * cg], ad_b = ((const float4*)a_d2)[2 * cg + 1];
    #pragma unroll
    for (int m = 0; m < 4; m++) {
        const int n = n0 + 4 * ng + m;
        float ps = acc[m][0].x * as_a.x + acc[m][0].y * as_a.y + acc[m][0].z * as_a.z + acc[m][0].w * as_a.w
                 + acc[m][1].x * as_b.x + acc[m][1].y * as_b.y + acc[m][1].z * as_b.z + acc[m][1].w * as_b.w;
        float pd = acc[m][0].x * ad_a.x + acc[m][0].y * ad_a.y + acc[m][0].z * ad_a.z + acc[m][0].w * ad_a.w
                 + acc[m][1].x * ad_b.x + acc[m][1].y * ad_b.y + acc[m][1].z * ad_b.z + acc[m][1].w * ad_b.w;
        ps += __shfl_xor(ps, 1); ps += __shfl_xor(ps, 2); ps += __shfl_xor(ps, 4);
        pd += __shfl_xor(pd, 1); pd += __shfl_xor(pd, 2); pd += __shfl_xor(pd, 4);
        if (n < N_NODES) {
            uint2 pk;
            pk.x = f2bf(acc[m][0].x) | (f2bf(acc[m][0].y) << 16);
            pk.y = f2bf(acc[m][0].z) | (f2bf(acc[m][0].w) << 16);
            uint2 pk2;
            pk2.x = f2bf(acc[m][1].x) | (f2bf(acc[m][1].y) << 16);
            pk2.y = f2bf(acc[m][1].z) | (f2bf(acc[m][1].w) << 16);
            uint4 pk4 = make_uint4(pk.x, pk.y, pk2.x, pk2.y);
            ((uint4*)h2b)[n * 8 + cg] = pk4;
            if (cg == 0) { as2[n] = ps; ad2[n] = pd; }
        }
    }
}

// ---------------------------------------------------------------------------
// Aggregation layer 2: 8 threads/node, 8 channels each. (unchanged)
// ---------------------------------------------------------------------------
__global__ __launch_bounds__(256) void k_aggr2(
    const int* __restrict__ rowptr, const int* __restrict__ csr_src,
    const float* __restrict__ as2, const float* __restrict__ ad2,
    const uint4* __restrict__ h2u4, float* __restrict__ acc2)
{
    const int d  = blockIdx.x * 32 + (threadIdx.x >> 3);
    const int c8 = threadIdx.x & 7;
    if (d >= N_NODES) return;
    const int r0 = rowptr[d], r1 = rowptr[d + 1];
    const float adv = ad2[d];
    float den = 0.f;
    float acc[8];
    #pragma unroll
    for (int m = 0; m < 8; m++) acc[m] = 0.f;
    int i = r0;
    for (; i + 2 <= r1; i += 2) {
        const int s0 = csr_src[i], s1 = csr_src[i + 1];
        const float e0 = as2[s0], e1 = as2[s1];
        const uint4 u0 = h2u4[s0 * 8 + c8];
        const uint4 u1 = h2u4[s1 * 8 + c8];
        const float w0 = expf(lrelu(e0 + adv));
        const float w1 = expf(lrelu(e1 + adv));
        den += w0 + w1;
        acc[0] = fmaf(bflo(u0.x), w0, acc[0]); acc[1] = fmaf(bfhi(u0.x), w0, acc[1]);
        acc[2] = fmaf(bflo(u0.y), w0, acc[2]); acc[3] = fmaf(bfhi(u0.y), w0, acc[3]);
        acc[4] = fmaf(bflo(u0.z), w0, acc[4]); acc[5] = fmaf(bfhi(u0.z), w0, acc[5]);
        acc[6] = fmaf(bflo(u0.w), w0, acc[6]); acc[7] = fmaf(bfhi(u0.w), w0, acc[7]);
        acc[0] = fmaf(bflo(u1.x), w1, acc[0]); acc[1] = fmaf(bfhi(u1.x), w1, acc[1]);
        acc[2] = fmaf(bflo(u1.y), w1, acc[2]); acc[3] = fmaf(bfhi(u1.y), w1, acc[3]);
        acc[4] = fmaf(bflo(u1.z), w1, acc[4]); acc[5] = fmaf(bfhi(u1.z), w1, acc[5]);
        acc[6] = fmaf(bflo(u1.w), w1, acc[6]); acc[7] = fmaf(bfhi(u1.w), w1, acc[7]);
    }
    if (i < r1) {
        const int s = csr_src[i];
        const float w = expf(lrelu(as2[s] + adv));
        const uint4 u = h2u4[s * 8 + c8];
        den += w;
        acc[0] = fmaf(bflo(u.x), w, acc[0]); acc[1] = fmaf(bfhi(u.x), w, acc[1]);
        acc[2] = fmaf(bflo(u.y), w, acc[2]); acc[3] = fmaf(bfhi(u.y), w, acc[3]);
        acc[4] = fmaf(bflo(u.z), w, acc[4]); acc[5] = fmaf(bfhi(u.z), w, acc[5]);
        acc[6] = fmaf(bflo(u.w), w, acc[6]); acc[7] = fmaf(bfhi(u.w), w, acc[7]);
    }
    const float inv = 1.f / (den + 1e-16f);
    float4 o0 = make_float4(acc[0] * inv, acc[1] * inv, acc[2] * inv, acc[3] * inv);
    float4 o1 = make_float4(acc[4] * inv, acc[5] * inv, acc[6] * inv, acc[7] * inv);
    ((float4*)acc2)[d * 16 + 2 * c8 + 0] = o0;
    ((float4*)acc2)[d * 16 + 2 * c8 + 1] = o1;
}

// ---------------------------------------------------------------------------
// K7: o = elu(acc2+b2); p = relu(o@pw1+pb1); out = p@pw2+pb2. (unchanged)
// ---------------------------------------------------------------------------
__global__ __launch_bounds__(256, 2) void k_out(
    const float* __restrict__ acc2, const float* __restrict__ b2,
    const float* __restrict__ pw1, const float* __restrict__ pb1,
    const float* __restrict__ pw2, const float* __restrict__ pb2,
    float* __restrict__ out)
{
    __shared__ float s1[64 * 64];
    __shared__ float s2[64 * 64];
    __shared__ float so[64][68];
    __shared__ float sp[64][68];
    const int tid = threadIdx.x;
    for (int i = tid; i < 1024; i += 256) {
        ((float4*)s1)[i] = ((const float4*)pw1)[i];
        ((float4*)s2)[i] = ((const float4*)pw2)[i];
    }
    const int cg = tid & 15;
    const int ng = tid >> 4;
    const float4 pb1_4 = ((const float4*)pb1)[cg];
    const float4 pb2_4 = ((const float4*)pb2)[cg];
    const int nGroups = (N_NODES + 63) / 64;   // 782
    for (int g = blockIdx.x; g < nGroups; g += gridDim.x) {
        const int n0 = g * 64;
        __syncthreads();
        #pragma unroll
        for (int j = 0; j < 4; j++) {
            const int i = tid + 256 * j;
            const int node = i >> 4, quad = i & 15;
            const int n = n0 + node;
            float4 v = make_float4(0.f, 0.f, 0.f, 0.f);
            if (n < N_NODES) {
                v = ((const float4*)acc2)[n * 16 + quad];
                const float4 bb = ((const float4*)b2)[quad];
                v.x = eluf(v.x + bb.x);
                v.y = eluf(v.y + bb.y);
                v.z = eluf(v.z + bb.z);
                v.w = eluf(v.w + bb.w);
            }
            *(float4*)&so[node][4 * quad] = v;
        }
        __syncthreads();
        float4 p[4];
        #pragma unroll
        for (int m = 0; m < 4; m++) p[m] = pb1_4;
        #pragma unroll 8
        for (int k = 0; k < 64; k++) {
            const float4 w = *(const float4*)&s1[k * 64 + 4 * cg];
            #pragma unroll
            for (int m = 0; m < 4; m++) {
                const float xv = so[4 * ng + m][k];
                p[m].x = fmaf(xv, w.x, p[m].x);
                p[m].y = fmaf(xv, w.y, p[m].y);
                p[m].z = fmaf(xv, w.z, p[m].z);
                p[m].w = fmaf(xv, w.w, p[m].w);
            }
        }
        #pragma unroll
        for (int m = 0; m < 4; m++) {
            p[m].x = fmaxf(p[m].x, 0.f); p[m].y = fmaxf(p[m].y, 0.f);
            p[m].z = fmaxf(p[m].z, 0.f); p[m].w = fmaxf(p[m].w, 0.f);
            *(float4*)&sp[4 * ng + m][4 * cg] = p[m];
        }
        __syncthreads();
        float4 o[4];
        #pragma unroll
        for (int m = 0; m < 4; m++) o[m] = pb2_4;
        #pragma unroll 8
        for (int k = 0; k < 64; k++) {
            const float4 w = *(const float4*)&s2[k * 64 + 4 * cg];
            #pragma unroll
            for (int m = 0; m < 4; m++) {
                const float xv = sp[4 * ng + m][k];
                o[m].x = fmaf(xv, w.x, o[m].x);
                o[m].y = fmaf(xv, w.y, o[m].y);
                o[m].z = fmaf(xv, w.z, o[m].z);
                o[m].w = fmaf(xv, w.w, o[m].w);
            }
        }
        #pragma unroll
        for (int m = 0; m < 4; m++) {
            const int n = n0 + 4 * ng + m;
            if (n < N_NODES) ((float4*)out)[n * 16 + cg] = o[m];
        }
    }
}

// ---------------------------------------------------------------------------
extern "C" void kernel_launch(void* const* d_in, const int* in_sizes, int n_in,
                              void* d_out, int out_size, void* d_ws, size_t ws_size,
                              hipStream_t stream)
{
    const float* x      = (const float*)d_in[0];
    const int*   ei     = (const int*)d_in[1];   // [2, E] int32
    const int*   src    = ei;
    const int*   dst    = ei + N_EDGES;
    const float* W1     = (const float*)d_in[2];
    const float* a_src1 = (const float*)d_in[3];
    const float* a_dst1 = (const float*)d_in[4];
    const float* b1     = (const float*)d_in[5];
    const float* W2     = (const float*)d_in[6];
    const float* a_src2 = (const float*)d_in[7];
    const float* a_dst2 = (const float*)d_in[8];
    const float* b2     = (const float*)d_in[9];
    const float* pw1    = (const float*)d_in[10];
    const float* pb1    = (const float*)d_in[11];
    const float* pw2    = (const float*)d_in[12];
    const float* pb2    = (const float*)d_in[13];

    // Workspace layout. part first (8B align from d_ws base).
    uint2* part  = (uint2*)d_ws;          // ET uint2
    int* ibase   = (int*)(part + ET);
    int* rowptr  = ibase;                 // 50,001
    int* C       = rowptr + 50001;        // NBUCK*NBLK = 200,192
    int* Cs      = C + 200192;            // 200,192
    int* bsum2   = Cs + 200192;           // 782
    int* boff2   = bsum2 + 782;           // 783 (+2 pad -> 785)
    int* csr_src = boff2 + 785;           // 850,000
    unsigned* h1b = (unsigned*)(csr_src + 850000);  // N*64 uints (bf16 x2)
    unsigned* h2b = h1b + 3200000;                  // N*32 uints
    float* fws   = (float*)(h2b + 1600000);
    float* as1   = fws;                   // N*4
    float* ad1   = as1 + 200000;          // N*4
    float* acc1  = ad1 + 200000;          // N*128
    float* as2   = acc1 + 6400000;        // N
    float* ad2   = as2 + 50000;           // N
    float* acc2  = ad2 + 50000;           // N*64

    // CSR build — atomic-free radix partition (reused by both layers).
    k_count<<<NBLK, 256, 0, stream>>>(dst, C);
    k_bsumA<<<NBUCK, 256, 0, stream>>>(C, bsum2);
    k_bscanB<<<1, 1024, 0, stream>>>(bsum2, boff2);
    k_cscanC<<<NBUCK, 256, 0, stream>>>(C, boff2, Cs);
    k_part2<<<NBLK, 256, 0, stream>>>(src, dst, Cs, part);
    k_scat2<<<NBUCK, 256, 0, stream>>>(boff2, part, rowptr, csr_src);

    // Layer 1 (MFMA GEMM)
    k_gemm1<<<(N_NODES + 63) / 64, 256, 0, stream>>>(x, W1, a_src1, a_dst1, h1b, as1, ad1);
    k_aggr1<<<N_NODES / 16, 256, 0, stream>>>(rowptr, csr_src, as1, ad1,
                                              (const uint4*)h1b, acc1);

    // Layer 2
    k_layer2<<<(N_NODES + 127) / 128, 256, 0, stream>>>(acc1, b1, W2, a_src2, a_dst2, h2b, as2, ad2);
    k_aggr2<<<(N_NODES + 31) / 32, 256, 0, stream>>>(rowptr, csr_src, as2, ad2,
                                                     (const uint4*)h2b, acc2);

    // Output MLP
    k_out<<<782, 256, 0, stream>>>(acc2, b2, pw1, pb1, pw2, pb2, (float*)d_out);
}

// Round 14
// 247.073 us; speedup vs baseline: 1.1567x; 1.0466x over previous
//
#include <hip/hip_runtime.h>
#include <math.h>

// Problem constants (from reference)
#define N_NODES 50000
#define N_EDGES 800000
#define ET (N_EDGES + N_NODES)   // edges + self loops = 850000
#define IN_DIM 128
#define HID 128
#define OUT_DIM 64
#define BW 64                              // bucket width (dst nodes)
#define NBUCK ((N_NODES + BW - 1) / BW)    // 782 buckets
#define NBLK 256                           // partition blocks
#define EPB 3328                           // edges per partition block (13*256)

typedef __attribute__((ext_vector_type(8))) short bf16x8;
typedef __attribute__((ext_vector_type(4))) float f32x4;

__device__ __forceinline__ float lrelu(float x){ return x >= 0.f ? x : 0.2f * x; }
__device__ __forceinline__ float eluf(float x){ return x > 0.f ? x : expm1f(x); }
// RNE float->bf16 (finite inputs)
__device__ __forceinline__ unsigned f2bf(float f){
    unsigned u = __float_as_uint(f);
    return (u + 0x7fffu + ((u >> 16) & 1u)) >> 16;
}
__device__ __forceinline__ float bflo(unsigned u){ return __uint_as_float(u << 16); }
__device__ __forceinline__ float bfhi(unsigned u){ return __uint_as_float(u & 0xffff0000u); }

// ---------------------------------------------------------------------------
// CSR build, atomic-free radix style (unchanged).
// ---------------------------------------------------------------------------
__global__ __launch_bounds__(256) void k_count(const int* __restrict__ dst, int* __restrict__ C)
{
    __shared__ int cnt[NBUCK];
    const int tid = threadIdx.x, blk = blockIdx.x;
    for (int i = tid; i < NBUCK; i += 256) cnt[i] = 0;
    __syncthreads();
    #pragma unroll
    for (int j = 0; j < EPB / 256; j++) {
        const int e = blk * EPB + j * 256 + tid;
        if (e < ET) {
            const int d = (e < N_EDGES) ? dst[e] : (e - N_EDGES);
            atomicAdd(&cnt[d >> 6], 1);
        }
    }
    __syncthreads();
    for (int b = tid; b < NBUCK; b += 256) C[b * NBLK + blk] = cnt[b];
}

__global__ __launch_bounds__(256) void k_bsumA(const int* __restrict__ C, int* __restrict__ bsum2)
{
    __shared__ int red[4];
    int v = C[blockIdx.x * NBLK + threadIdx.x];
    #pragma unroll
    for (int off = 32; off > 0; off >>= 1) v += __shfl_down(v, off);
    if ((threadIdx.x & 63) == 0) red[threadIdx.x >> 6] = v;
    __syncthreads();
    if (threadIdx.x == 0) bsum2[blockIdx.x] = red[0] + red[1] + red[2] + red[3];
}

__global__ __launch_bounds__(1024) void k_bscanB(const int* __restrict__ bsum2, int* __restrict__ boff2)
{
    __shared__ int part[1024];
    const int t = threadIdx.x;
    int v = (t < NBUCK) ? bsum2[t] : 0;
    part[t] = v;
    __syncthreads();
    #pragma unroll
    for (int d = 1; d < 1024; d <<= 1) {
        int add = (t >= d) ? part[t - d] : 0;
        __syncthreads();
        part[t] += add;
        __syncthreads();
    }
    if (t < NBUCK) boff2[t] = part[t] - v;   // exclusive
    if (t == 0) boff2[NBUCK] = ET;
}

__global__ __launch_bounds__(256) void k_cscanC(const int* __restrict__ C,
                                                const int* __restrict__ boff2,
                                                int* __restrict__ Cs)
{
    __shared__ int part[256];
    const int t = threadIdx.x, b = blockIdx.x;
    int v = C[b * NBLK + t];
    part[t] = v;
    __syncthreads();
    #pragma unroll
    for (int d = 1; d < 256; d <<= 1) {
        int add = (t >= d) ? part[t - d] : 0;
        __syncthreads();
        part[t] += add;
        __syncthreads();
    }
    Cs[b * NBLK + t] = boff2[b] + part[t] - v;
}

__global__ __launch_bounds__(256) void k_part2(const int* __restrict__ src,
                                               const int* __restrict__ dst,
                                               const int* __restrict__ Cs,
                                               uint2* __restrict__ part)
{
    __shared__ int base[NBUCK];
    __shared__ int cnt[NBUCK];
    const int tid = threadIdx.x, blk = blockIdx.x;
    for (int b = tid; b < NBUCK; b += 256) { base[b] = Cs[b * NBLK + blk]; cnt[b] = 0; }
    __syncthreads();
    #pragma unroll
    for (int j = 0; j < EPB / 256; j++) {
        const int e = blk * EPB + j * 256 + tid;
        if (e < ET) {
            int s, d;
            if (e < N_EDGES) { s = src[e]; d = dst[e]; } else { s = d = e - N_EDGES; }
            const int b = d >> 6;
            const int r = atomicAdd(&cnt[b], 1);
            part[base[b] + r] = make_uint2((unsigned)d, (unsigned)s);
        }
    }
}

__global__ __launch_bounds__(256) void k_scat2(const int* __restrict__ boff2,
                                               const uint2* __restrict__ part,
                                               int* __restrict__ rowptr,
                                               int* __restrict__ csr_src)
{
    __shared__ int cnt64[BW];
    __shared__ int nbase[BW];
    const int b = blockIdx.x, tid = threadIdx.x;
    const int n0 = b * BW;
    const int lo = boff2[b], hi = boff2[b + 1];
    if (tid < BW) cnt64[tid] = 0;
    __syncthreads();
    for (int i = lo + tid; i < hi; i += 256) {
        atomicAdd(&cnt64[part[i].x & (BW - 1)], 1);
    }
    __syncthreads();
    if (tid < BW) {
        int v = cnt64[tid];
        int incl = v;
        #pragma unroll
        for (int off = 1; off < 64; off <<= 1) {
            int t2 = __shfl_up(incl, off);
            if (tid >= off) incl += t2;
        }
        const int excl = incl - v;
        nbase[tid] = excl;
        const int n = n0 + tid;
        if (n < N_NODES) rowptr[n] = lo + excl;
        cnt64[tid] = 0;
    }
    if (b == 0 && tid == 0) rowptr[N_NODES] = ET;
    __syncthreads();
    for (int i = lo + tid; i < hi; i += 256) {
        const uint2 p = part[i];
        const int dn = (int)p.x & (BW - 1);
        const int r = atomicAdd(&cnt64[dn], 1);
        csr_src[lo + nbase[dn] + r] = (int)p.y;
    }
}

// ---------------------------------------------------------------------------
// K1 (MFMA): h1 = x @ W1 [N,128] -> bf16 table + fp32 logits. (R13, unchanged)
// ---------------------------------------------------------------------------
__global__ __launch_bounds__(256, 2) void k_gemm1(
    const float* __restrict__ x, const float* __restrict__ W1,
    const float* __restrict__ a_s, const float* __restrict__ a_d,
    unsigned* __restrict__ h1b, float* __restrict__ as1, float* __restrict__ ad1)
{
    __shared__ unsigned sWt[128 * 68];   // W^T bf16 pairs: [n][kp], 34.8 KB
    __shared__ unsigned sxb[64 * 68];    // x   bf16 pairs: [node][kp], 17.4 KB
    const int tid = threadIdx.x;
    const int wave = tid >> 6;           // 0..3 -> M-tile (16 nodes)
    const int lane = tid & 63;
    const int ll   = lane & 15;
    const int quad = lane >> 4;
    const int n0 = blockIdx.x * 64;

    for (int idx = tid; idx < 8192; idx += 256) {
        const int n = idx & 127, kp = idx >> 7;
        const float w0 = W1[(2 * kp) * 128 + n];
        const float w1 = W1[(2 * kp + 1) * 128 + n];
        sWt[n * 68 + kp] = f2bf(w0) | (f2bf(w1) << 16);
    }
    for (int idx = tid; idx < 4096; idx += 256) {
        const int node = idx >> 6, kp = idx & 63;
        const int n = n0 + node;
        unsigned pk = 0;
        if (n < N_NODES) {
            const float x0 = x[n * 128 + 2 * kp];
            const float x1 = x[n * 128 + 2 * kp + 1];
            pk = f2bf(x0) | (f2bf(x1) << 16);
        }
        sxb[node * 68 + kp] = pk;
    }
    __syncthreads();

    f32x4 acc[8];
    #pragma unroll
    for (int t = 0; t < 8; t++) acc[t] = (f32x4){0.f, 0.f, 0.f, 0.f};

    #pragma unroll
    for (int kk = 0; kk < 4; kk++) {
        const int kpo = 16 * kk + 4 * quad;
        const bf16x8 a = *(const bf16x8*)&sxb[(16 * wave + ll) * 68 + kpo];
        #pragma unroll
        for (int t = 0; t < 8; t++) {
            const bf16x8 b = *(const bf16x8*)&sWt[(16 * t + ll) * 68 + kpo];
            acc[t] = __builtin_amdgcn_mfma_f32_16x16x32_bf16(a, b, acc[t], 0, 0, 0);
        }
    }

    float as_v[8], ad_v[8];
    #pragma unroll
    for (int t = 0; t < 8; t++) { as_v[t] = a_s[16 * t + ll]; ad_v[t] = a_d[16 * t + ll]; }
    unsigned short* h1u = (unsigned short*)h1b;
    #pragma unroll
    for (int r = 0; r < 4; r++) {
        const int n = n0 + 16 * wave + 4 * quad + r;
        float ps0 = acc[0][r] * as_v[0] + acc[1][r] * as_v[1];
        float ps1 = acc[2][r] * as_v[2] + acc[3][r] * as_v[3];
        float ps2 = acc[4][r] * as_v[4] + acc[5][r] * as_v[5];
        float ps3 = acc[6][r] * as_v[6] + acc[7][r] * as_v[7];
        float pd0 = acc[0][r] * ad_v[0] + acc[1][r] * ad_v[1];
        float pd1 = acc[2][r] * ad_v[2] + acc[3][r] * ad_v[3];
        float pd2 = acc[4][r] * ad_v[4] + acc[5][r] * ad_v[5];
        float pd3 = acc[6][r] * ad_v[6] + acc[7][r] * ad_v[7];
        #pragma unroll
        for (int off = 1; off < 16; off <<= 1) {
            ps0 += __shfl_xor(ps0, off); ps1 += __shfl_xor(ps1, off);
            ps2 += __shfl_xor(ps2, off); ps3 += __shfl_xor(ps3, off);
            pd0 += __shfl_xor(pd0, off); pd1 += __shfl_xor(pd1, off);
            pd2 += __shfl_xor(pd2, off); pd3 += __shfl_xor(pd3, off);
        }
        if (n < N_NODES) {
            #pragma unroll
            for (int t = 0; t < 8; t++)
                h1u[n * 128 + 16 * t + ll] = (unsigned short)f2bf(acc[t][r]);
            if (ll == 0) {
                as1[n * 4 + 0] = ps0; as1[n * 4 + 1] = ps1;
                as1[n * 4 + 2] = ps2; as1[n * 4 + 3] = ps3;
                ad1[n * 4 + 0] = pd0; ad1[n * 4 + 1] = pd1;
                ad1[n * 4 + 2] = pd2; ad1[n * 4 + 3] = pd3;
            }
        }
    }
}

// ---------------------------------------------------------------------------
// Aggregation layer 1: 16 threads/node, 8 channels each. (unchanged)
// ---------------------------------------------------------------------------
__global__ __launch_bounds__(256) void k_aggr1(
    const int* __restrict__ rowptr, const int* __restrict__ csr_src,
    const float* __restrict__ as1, const float* __restrict__ ad1,
    const uint4* __restrict__ h1u4, float* __restrict__ acc1)
{
    const int d  = blockIdx.x * 16 + (threadIdx.x >> 4);
    const int c8 = threadIdx.x & 15;
    const int hd = c8 >> 2;
    const int r0 = rowptr[d], r1 = rowptr[d + 1];
    const float adv = ad1[d * 4 + hd];
    float den = 0.f;
    float acc[8];
    #pragma unroll
    for (int m = 0; m < 8; m++) acc[m] = 0.f;
    int i = r0;
    for (; i + 2 <= r1; i += 2) {
        const int s0 = csr_src[i], s1 = csr_src[i + 1];
        const float e0 = as1[s0 * 4 + hd], e1 = as1[s1 * 4 + hd];
        const uint4 u0 = h1u4[s0 * 16 + c8];
        const uint4 u1 = h1u4[s1 * 16 + c8];
        const float w0 = expf(lrelu(e0 + adv));
        const float w1 = expf(lrelu(e1 + adv));
        den += w0 + w1;
        acc[0] = fmaf(bflo(u0.x), w0, acc[0]); acc[1] = fmaf(bfhi(u0.x), w0, acc[1]);
        acc[2] = fmaf(bflo(u0.y), w0, acc[2]); acc[3] = fmaf(bfhi(u0.y), w0, acc[3]);
        acc[4] = fmaf(bflo(u0.z), w0, acc[4]); acc[5] = fmaf(bfhi(u0.z), w0, acc[5]);
        acc[6] = fmaf(bflo(u0.w), w0, acc[6]); acc[7] = fmaf(bfhi(u0.w), w0, acc[7]);
        acc[0] = fmaf(bflo(u1.x), w1, acc[0]); acc[1] = fmaf(bfhi(u1.x), w1, acc[1]);
        acc[2] = fmaf(bflo(u1.y), w1, acc[2]); acc[3] = fmaf(bfhi(u1.y), w1, acc[3]);
        acc[4] = fmaf(bflo(u1.z), w1, acc[4]); acc[5] = fmaf(bfhi(u1.z), w1, acc[5]);
        acc[6] = fmaf(bflo(u1.w), w1, acc[6]); acc[7] = fmaf(bfhi(u1.w), w1, acc[7]);
    }
    if (i < r1) {
        const int s = csr_src[i];
        const float w = expf(lrelu(as1[s * 4 + hd] + adv));
        const uint4 u = h1u4[s * 16 + c8];
        den += w;
        acc[0] = fmaf(bflo(u.x), w, acc[0]); acc[1] = fmaf(bfhi(u.x), w, acc[1]);
        acc[2] = fmaf(bflo(u.y), w, acc[2]); acc[3] = fmaf(bfhi(u.y), w, acc[3]);
        acc[4] = fmaf(bflo(u.z), w, acc[4]); acc[5] = fmaf(bfhi(u.z), w, acc[5]);
        acc[6] = fmaf(bflo(u.w), w, acc[6]); acc[7] = fmaf(bfhi(u.w), w, acc[7]);
    }
    const float inv = 1.f / (den + 1e-16f);
    float4 o0 = make_float4(acc[0] * inv, acc[1] * inv, acc[2] * inv, acc[3] * inv);
    float4 o1 = make_float4(acc[4] * inv, acc[5] * inv, acc[6] * inv, acc[7] * inv);
    ((float4*)acc1)[d * 32 + 2 * c8 + 0] = o0;
    ((float4*)acc1)[d * 32 + 2 * c8 + 1] = o1;
}

// ---------------------------------------------------------------------------
// K4 (MFMA): hE = elu(acc1+b1); h2 = hE @ W2 [N,64] -> bf16 table + logits.
// 64 nodes/block, 256 threads (4 waves), 782 blocks. Wave = 16-node M-tile
// x full N=64 (4 accumulators), K=128 in 4 MFMA steps. W2^T and hE staged
// bf16 in LDS once (34.8 KB -> 4 blocks/CU), single barrier. Same verified
// fragment layouts as k_gemm1.
// ---------------------------------------------------------------------------
__global__ __launch_bounds__(256, 4) void k_layer2(
    const float* __restrict__ acc1, const float* __restrict__ b1,
    const float* __restrict__ W2, const float* __restrict__ a_s2, const float* __restrict__ a_d2,
    unsigned* __restrict__ h2b, float* __restrict__ as2, float* __restrict__ ad2)
{
    __shared__ unsigned sWt[64 * 68];   // W2^T bf16 pairs [n][kp], 17.4 KB
    __shared__ unsigned sxb[64 * 68];   // hE   bf16 pairs [node][kp], 17.4 KB
    const int tid = threadIdx.x;
    const int wave = tid >> 6;
    const int lane = tid & 63;
    const int ll   = lane & 15;
    const int quad = lane >> 4;
    const int n0 = blockIdx.x * 64;

    // Stage W2^T: 4096 uints. n = idx&63 (coalesced W2 reads), kp = idx>>6.
    for (int idx = tid; idx < 4096; idx += 256) {
        const int n = idx & 63, kp = idx >> 6;
        const float w0 = W2[(2 * kp) * 64 + n];
        const float w1 = W2[(2 * kp + 1) * 64 + n];
        sWt[n * 68 + kp] = f2bf(w0) | (f2bf(w1) << 16);
    }
    // Stage hE: 4096 uints. node = idx>>6, kp = idx&63 (coalesced acc1 reads).
    for (int idx = tid; idx < 4096; idx += 256) {
        const int node = idx >> 6, kp = idx & 63;
        const int n = n0 + node;
        unsigned pk = 0;
        if (n < N_NODES) {
            const float v0 = eluf(acc1[n * 128 + 2 * kp]     + b1[2 * kp]);
            const float v1 = eluf(acc1[n * 128 + 2 * kp + 1] + b1[2 * kp + 1]);
            pk = f2bf(v0) | (f2bf(v1) << 16);
        }
        sxb[node * 68 + kp] = pk;
    }
    __syncthreads();

    f32x4 acc[4];
    #pragma unroll
    for (int t = 0; t < 4; t++) acc[t] = (f32x4){0.f, 0.f, 0.f, 0.f};

    #pragma unroll
    for (int kk = 0; kk < 4; kk++) {
        const int kpo = 16 * kk + 4 * quad;
        const bf16x8 a = *(const bf16x8*)&sxb[(16 * wave + ll) * 68 + kpo];
        #pragma unroll
        for (int t = 0; t < 4; t++) {
            const bf16x8 b = *(const bf16x8*)&sWt[(16 * t + ll) * 68 + kpo];
            acc[t] = __builtin_amdgcn_mfma_f32_16x16x32_bf16(a, b, acc[t], 0, 0, 0);
        }
    }

    // Epilogue: lane holds cols 16t+ll, rows 4*quad+r of the wave's M-tile.
    float as_v[4], ad_v[4];
    #pragma unroll
    for (int t = 0; t < 4; t++) { as_v[t] = a_s2[16 * t + ll]; ad_v[t] = a_d2[16 * t + ll]; }
    unsigned short* h2u = (unsigned short*)h2b;
    #pragma unroll
    for (int r = 0; r < 4; r++) {
        const int n = n0 + 16 * wave + 4 * quad + r;
        float ps = acc[0][r] * as_v[0] + acc[1][r] * as_v[1]
                 + acc[2][r] * as_v[2] + acc[3][r] * as_v[3];
        float pd = acc[0][r] * ad_v[0] + acc[1][r] * ad_v[1]
                 + acc[2][r] * ad_v[2] + acc[3][r] * ad_v[3];
        #pragma unroll
        for (int off = 1; off < 16; off <<= 1) {
            ps += __shfl_xor(ps, off);
            pd += __shfl_xor(pd, off);
        }
        if (n < N_NODES) {
            #pragma unroll
            for (int t = 0; t < 4; t++)
                h2u[n * 64 + 16 * t + ll] = (unsigned short)f2bf(acc[t][r]);
            if (ll == 0) { as2[n] = ps; ad2[n] = pd; }
        }
    }
}

// ---------------------------------------------------------------------------
// Aggregation layer 2: 8 threads/node, 8 channels each. (unchanged)
// ---------------------------------------------------------------------------
__global__ __launch_bounds__(256) void k_aggr2(
    const int* __restrict__ rowptr, const int* __restrict__ csr_src,
    const float* __restrict__ as2, const float* __restrict__ ad2,
    const uint4* __restrict__ h2u4, float* __restrict__ acc2)
{
    const int d  = blockIdx.x * 32 + (threadIdx.x >> 3);
    const int c8 = threadIdx.x & 7;
    if (d >= N_NODES) return;
    const int r0 = rowptr[d], r1 = rowptr[d + 1];
    const float adv = ad2[d];
    float den = 0.f;
    float acc[8];
    #pragma unroll
    for (int m = 0; m < 8; m++) acc[m] = 0.f;
    int i = r0;
    for (; i + 2 <= r1; i += 2) {
        const int s0 = csr_src[i], s1 = csr_src[i + 1];
        const float e0 = as2[s0], e1 = as2[s1];
        const uint4 u0 = h2u4[s0 * 8 + c8];
        const uint4 u1 = h2u4[s1 * 8 + c8];
        const float w0 = expf(lrelu(e0 + adv));
        const float w1 = expf(lrelu(e1 + adv));
        den += w0 + w1;
        acc[0] = fmaf(bflo(u0.x), w0, acc[0]); acc[1] = fmaf(bfhi(u0.x), w0, acc[1]);
        acc[2] = fmaf(bflo(u0.y), w0, acc[2]); acc[3] = fmaf(bfhi(u0.y), w0, acc[3]);
        acc[4] = fmaf(bflo(u0.z), w0, acc[4]); acc[5] = fmaf(bfhi(u0.z), w0, acc[5]);
        acc[6] = fmaf(bflo(u0.w), w0, acc[6]); acc[7] = fmaf(bfhi(u0.w), w0, acc[7]);
        acc[0] = fmaf(bflo(u1.x), w1, acc[0]); acc[1] = fmaf(bfhi(u1.x), w1, acc[1]);
        acc[2] = fmaf(bflo(u1.y), w1, acc[2]); acc[3] = fmaf(bfhi(u1.y), w1, acc[3]);
        acc[4] = fmaf(bflo(u1.z), w1, acc[4]); acc[5] = fmaf(bfhi(u1.z), w1, acc[5]);
        acc[6] = fmaf(bflo(u1.w), w1, acc[6]); acc[7] = fmaf(bfhi(u1.w), w1, acc[7]);
    }
    if (i < r1) {
        const int s = csr_src[i];
        const float w = expf(lrelu(as2[s] + adv));
        const uint4 u = h2u4[s * 8 + c8];
        den += w;
        acc[0] = fmaf(bflo(u.x), w, acc[0]); acc[1] = fmaf(bfhi(u.x), w, acc[1]);
        acc[2] = fmaf(bflo(u.y), w, acc[2]); acc[3] = fmaf(bfhi(u.y), w, acc[3]);
        acc[4] = fmaf(bflo(u.z), w, acc[4]); acc[5] = fmaf(bfhi(u.z), w, acc[5]);
        acc[6] = fmaf(bflo(u.w), w, acc[6]); acc[7] = fmaf(bfhi(u.w), w, acc[7]);
    }
    const float inv = 1.f / (den + 1e-16f);
    float4 o0 = make_float4(acc[0] * inv, acc[1] * inv, acc[2] * inv, acc[3] * inv);
    float4 o1 = make_float4(acc[4] * inv, acc[5] * inv, acc[6] * inv, acc[7] * inv);
    ((float4*)acc2)[d * 16 + 2 * c8 + 0] = o0;
    ((float4*)acc2)[d * 16 + 2 * c8 + 1] = o1;
}

// ---------------------------------------------------------------------------
// K7: o = elu(acc2+b2); p = relu(o@pw1+pb1); out = p@pw2+pb2. (unchanged)
// ---------------------------------------------------------------------------
__global__ __launch_bounds__(256, 2) void k_out(
    const float* __restrict__ acc2, const float* __restrict__ b2,
    const float* __restrict__ pw1, const float* __restrict__ pb1,
    const float* __restrict__ pw2, const float* __restrict__ pb2,
    float* __restrict__ out)
{
    __shared__ float s1[64 * 64];
    __shared__ float s2[64 * 64];
    __shared__ float so[64][68];
    __shared__ float sp[64][68];
    const int tid = threadIdx.x;
    for (int i = tid; i < 1024; i += 256) {
        ((float4*)s1)[i] = ((const float4*)pw1)[i];
        ((float4*)s2)[i] = ((const float4*)pw2)[i];
    }
    const int cg = tid & 15;
    const int ng = tid >> 4;
    const float4 pb1_4 = ((const float4*)pb1)[cg];
    const float4 pb2_4 = ((const float4*)pb2)[cg];
    const int nGroups = (N_NODES + 63) / 64;   // 782
    for (int g = blockIdx.x; g < nGroups; g += gridDim.x) {
        const int n0 = g * 64;
        __syncthreads();
        #pragma unroll
        for (int j = 0; j < 4; j++) {
            const int i = tid + 256 * j;
            const int node = i >> 4, quad = i & 15;
            const int n = n0 + node;
            float4 v = make_float4(0.f, 0.f, 0.f, 0.f);
            if (n < N_NODES) {
                v = ((const float4*)acc2)[n * 16 + quad];
                const float4 bb = ((const float4*)b2)[quad];
                v.x = eluf(v.x + bb.x);
                v.y = eluf(v.y + bb.y);
                v.z = eluf(v.z + bb.z);
                v.w = eluf(v.w + bb.w);
            }
            *(float4*)&so[node][4 * quad] = v;
        }
        __syncthreads();
        float4 p[4];
        #pragma unroll
        for (int m = 0; m < 4; m++) p[m] = pb1_4;
        #pragma unroll 8
        for (int k = 0; k < 64; k++) {
            const float4 w = *(const float4*)&s1[k * 64 + 4 * cg];
            #pragma unroll
            for (int m = 0; m < 4; m++) {
                const float xv = so[4 * ng + m][k];
                p[m].x = fmaf(xv, w.x, p[m].x);
                p[m].y = fmaf(xv, w.y, p[m].y);
                p[m].z = fmaf(xv, w.z, p[m].z);
                p[m].w = fmaf(xv, w.w, p[m].w);
            }
        }
        #pragma unroll
        for (int m = 0; m < 4; m++) {
            p[m].x = fmaxf(p[m].x, 0.f); p[m].y = fmaxf(p[m].y, 0.f);
            p[m].z = fmaxf(p[m].z, 0.f); p[m].w = fmaxf(p[m].w, 0.f);
            *(float4*)&sp[4 * ng + m][4 * cg] = p[m];
        }
        __syncthreads();
        float4 o[4];
        #pragma unroll
        for (int m = 0; m < 4; m++) o[m] = pb2_4;
        #pragma unroll 8
        for (int k = 0; k < 64; k++) {
            const float4 w = *(const float4*)&s2[k * 64 + 4 * cg];
            #pragma unroll
            for (int m = 0; m < 4; m++) {
                const float xv = sp[4 * ng + m][k];
                o[m].x = fmaf(xv, w.x, o[m].x);
                o[m].y = fmaf(xv, w.y, o[m].y);
                o[m].z = fmaf(xv, w.z, o[m].z);
                o[m].w = fmaf(xv, w.w, o[m].w);
            }
        }
        #pragma unroll
        for (int m = 0; m < 4; m++) {
            const int n = n0 + 4 * ng + m;
            if (n < N_NODES) ((float4*)out)[n * 16 + cg] = o[m];
        }
    }
}

// ---------------------------------------------------------------------------
extern "C" void kernel_launch(void* const* d_in, const int* in_sizes, int n_in,
                              void* d_out, int out_size, void* d_ws, size_t ws_size,
                              hipStream_t stream)
{
    const float* x      = (const float*)d_in[0];
    const int*   ei     = (const int*)d_in[1];   // [2, E] int32
    const int*   src    = ei;
    const int*   dst    = ei + N_EDGES;
    const float* W1     = (const float*)d_in[2];
    const float* a_src1 = (const float*)d_in[3];
    const float* a_dst1 = (const float*)d_in[4];
    const float* b1     = (const float*)d_in[5];
    const float* W2     = (const float*)d_in[6];
    const float* a_src2 = (const float*)d_in[7];
    const float* a_dst2 = (const float*)d_in[8];
    const float* b2     = (const float*)d_in[9];
    const float* pw1    = (const float*)d_in[10];
    const float* pb1    = (const float*)d_in[11];
    const float* pw2    = (const float*)d_in[12];
    const float* pb2    = (const float*)d_in[13];

    // Workspace layout. part first (8B align from d_ws base).
    uint2* part  = (uint2*)d_ws;          // ET uint2
    int* ibase   = (int*)(part + ET);
    int* rowptr  = ibase;                 // 50,001
    int* C       = rowptr + 50001;        // NBUCK*NBLK = 200,192
    int* Cs      = C + 200192;            // 200,192
    int* bsum2   = Cs + 200192;           // 782
    int* boff2   = bsum2 + 782;           // 783 (+2 pad -> 785)
    int* csr_src = boff2 + 785;           // 850,000
    unsigned* h1b = (unsigned*)(csr_src + 850000);  // N*64 uints (bf16 x2)
    unsigned* h2b = h1b + 3200000;                  // N*32 uints
    float* fws   = (float*)(h2b + 1600000);
    float* as1   = fws;                   // N*4
    float* ad1   = as1 + 200000;          // N*4
    float* acc1  = ad1 + 200000;          // N*128
    float* as2   = acc1 + 6400000;        // N
    float* ad2   = as2 + 50000;           // N
    float* acc2  = ad2 + 50000;           // N*64

    // CSR build — atomic-free radix partition (reused by both layers).
    k_count<<<NBLK, 256, 0, stream>>>(dst, C);
    k_bsumA<<<NBUCK, 256, 0, stream>>>(C, bsum2);
    k_bscanB<<<1, 1024, 0, stream>>>(bsum2, boff2);
    k_cscanC<<<NBUCK, 256, 0, stream>>>(C, boff2, Cs);
    k_part2<<<NBLK, 256, 0, stream>>>(src, dst, Cs, part);
    k_scat2<<<NBUCK, 256, 0, stream>>>(boff2, part, rowptr, csr_src);

    // Layer 1 (MFMA GEMM)
    k_gemm1<<<(N_NODES + 63) / 64, 256, 0, stream>>>(x, W1, a_src1, a_dst1, h1b, as1, ad1);
    k_aggr1<<<N_NODES / 16, 256, 0, stream>>>(rowptr, csr_src, as1, ad1,
                                              (const uint4*)h1b, acc1);

    // Layer 2 (MFMA GEMM)
    k_layer2<<<(N_NODES + 63) / 64, 256, 0, stream>>>(acc1, b1, W2, a_src2, a_dst2, h2b, as2, ad2);
    k_aggr2<<<(N_NODES + 31) / 32, 256, 0, stream>>>(rowptr, csr_src, as2, ad2,
                                                     (const uint4*)h2b, acc2);

    // Output MLP
    k_out<<<782, 256, 0, stream>>>(acc2, b2, pw1, pb1, pw2, pb2, (float*)d_out);
}